// Round 9
// baseline (241.450 us; speedup 1.0000x reference)
//
#include <hip/hip_runtime.h>
#include <math.h>

#define TOKENS    1024
#define IN_W      512
#define BLOCK_H   256
#define OUT_W     512
#define N_EXPERTS 64
#define TOPK      2
#define NSLOTS    (TOKENS * TOPK)
#define LIST_CAP  128     // ne ~ Binom(2048,1/64): mean 32, sigma 5.6; 128 is +17 sigma
#define T_CAP     8       // max tokens/pass; caps acc at 32 VGPR (spill-free 4-deep ring)
#define NGRP      4       // groups per expert -> grid 256 = 1 block/CU
#define XPAD      520     // x row stride (floats); broadcast reads, 0 conflicts (r1-verified)
#define VPAD      264     // v row stride

__device__ __forceinline__ void red_xor(float4& v, int m) {
    v.x += __shfl_xor(v.x, m); v.y += __shfl_xor(v.y, m);
    v.z += __shfl_xor(v.z, m); v.w += __shfl_xor(v.w, m);
}

__device__ __forceinline__ void fma4(float4& a, float s, const float4& w) {
    a.x = fmaf(s, w.x, a.x); a.y = fmaf(s, w.y, a.y);
    a.z = fmaf(s, w.z, a.z); a.w = fmaf(s, w.w, a.w);
}

// ---------------------------------------------------------------------------
// Routing v2 (verified r7): 1 token/block x 1024 blocks; wave = i-quarter;
// float4 loads 4 rows x 64 experts; zeroes this token's out row.
// ---------------------------------------------------------------------------
__global__ __launch_bounds__(256) void routing_kernel(
    const float* __restrict__ x, const float* __restrict__ noise,
    const float* __restrict__ mixer, const float* __restrict__ noisec,
    float* __restrict__ esc, int* __restrict__ counts, int* __restrict__ lists,
    float* __restrict__ out)
{
    __shared__ float xs[512];
    __shared__ float pm[4 * 64];
    __shared__ float pn[4 * 64];
    __shared__ float hs[64];
    const int t    = blockIdx.x;
    const int tid  = threadIdx.x;
    const int wave = tid >> 6, lane = tid & 63;
    const int rs   = lane >> 4;
    const int c    = lane & 15;

    if (tid < 128) {
        ((float4*)xs)[tid] = ((const float4*)(x + (size_t)t * IN_W))[tid];
        ((float4*)(out + (size_t)t * OUT_W))[tid] = make_float4(0.f, 0.f, 0.f, 0.f);
    }
    __syncthreads();

    float4 am = make_float4(0.f, 0.f, 0.f, 0.f), an = am;
    const float4* m4 = (const float4*)mixer;
    const float4* n4 = (const float4*)noisec;
    const int rbase = wave * 128;
    #pragma unroll 4
    for (int j = 0; j < 32; ++j) {
        const int r = rbase + j * 4 + rs;
        const float xv = xs[r];
        const float4 wm = m4[r * 16 + c];
        const float4 wn = n4[r * 16 + c];
        fma4(am, xv, wm);
        fma4(an, xv, wn);
    }
    red_xor(am, 16); red_xor(am, 32);
    red_xor(an, 16); red_xor(an, 32);
    if (lane < 16) {
        *(float4*)&pm[wave * 64 + lane * 4] = am;
        *(float4*)&pn[wave * 64 + lane * 4] = an;
    }
    __syncthreads();

    if (tid < 64) {
        const float am2 = pm[tid] + pm[64 + tid] + pm[128 + tid] + pm[192 + tid];
        const float an2 = pn[tid] + pn[64 + tid] + pn[128 + tid] + pn[192 + tid];
        const float sp = fmaxf(an2, 0.f) + log1pf(expf(-fabsf(an2)));
        hs[tid] = am2 + noise[(size_t)t * 64 + tid] * sp;
    }
    __syncthreads();

    if (tid == 0) {
        float b0 = -INFINITY, b1 = -INFINITY;
        int i0 = 0, i1 = 0;
        for (int i = 0; i < N_EXPERTS; ++i) {
            const float v = hs[i];
            if (v > b0)      { b1 = b0; i1 = i0; b0 = v; i0 = i; }
            else if (v > b1) { b1 = v; i1 = i; }
        }
        const float z   = expf(b1 - b0);
        const float inv = 1.f / (1.f + z);
        esc[t * 2 + 0] = inv;
        esc[t * 2 + 1] = z * inv;
        const int p0 = atomicAdd(&counts[i0], 1);
        if (p0 < LIST_CAP) lists[i0 * LIST_CAP + p0] = t * 2 + 0;
        const int p1 = atomicAdd(&counts[i1], 1);
        if (p1 < LIST_CAP) lists[i1 * LIST_CAP + p1] = t * 2 + 1;
    }
}

// ---------------------------------------------------------------------------
// Fused expert FFN, v10 = r1 structure with a register-feasible 4-deep ring
// prefetch. r2's failure decomposed: (a) copy-rotation held 8 float4 temps
// (32 VGPR) -- the ring below holds 4 (reload immediately after each reg's
// FMA block); (b) T=12 acc = 48 VGPR -- T_CAP=8 caps acc at 32. Total
// ~60 <= 64 VGPR: the in-flight-loads mechanism without the spill. ne>32
// experts (~47%) take a cheap second pass (T=4). All indices static under
// full unroll (rule 20).
// ---------------------------------------------------------------------------
template<int T>
__device__ __forceinline__ void run_pass(
    int nTok, int wave, int lane,
    const float4* __restrict__ w1v, const float4* __restrict__ w2v,
    const float4* __restrict__ b1v, const float4* __restrict__ b2v,
    const float* __restrict__ xs, float* __restrict__ vsm,
    const int* __restrict__ slotIds, const float* __restrict__ escv,
    float* __restrict__ out)
{
    // ---- phase 1: v = relu(x @ W1 + b1) ----
    // wave covers cols [wave*16, wave*16+16); lane = (r0 = lane>>2, c4l = lane&3)
    // row = s*16 + r0; 4-deep ring: wr_k reloaded right after its FMA block.
    {
        const int c4l = lane & 3, r0 = lane >> 2;
        float4 acc[T];
        #pragma unroll
        for (int t = 0; t < T; ++t) acc[t] = make_float4(0.f, 0.f, 0.f, 0.f);
        const float4* wp = w1v + (size_t)(r0 * 64 + wave * 4 + c4l);
        const float*  xb = xs + r0;
        float4 wr0 = wp[0], wr1 = wp[1024], wr2 = wp[2048], wr3 = wp[3072];
        #pragma unroll
        for (int sb = 0; sb < 32; sb += 4) {
            #pragma unroll
            for (int t = 0; t < T; ++t) fma4(acc[t], xb[t * XPAD + (sb + 0) * 16], wr0);
            if (sb < 28) wr0 = wp[(size_t)(sb + 4) * 1024];
            #pragma unroll
            for (int t = 0; t < T; ++t) fma4(acc[t], xb[t * XPAD + (sb + 1) * 16], wr1);
            if (sb < 28) wr1 = wp[(size_t)(sb + 5) * 1024];
            #pragma unroll
            for (int t = 0; t < T; ++t) fma4(acc[t], xb[t * XPAD + (sb + 2) * 16], wr2);
            if (sb < 28) wr2 = wp[(size_t)(sb + 6) * 1024];
            #pragma unroll
            for (int t = 0; t < T; ++t) fma4(acc[t], xb[t * XPAD + (sb + 3) * 16], wr3);
            if (sb < 28) wr3 = wp[(size_t)(sb + 7) * 1024];
        }
        #pragma unroll
        for (int t = 0; t < T; ++t) {      // reduce over r0 (lane bits 2..5)
            red_xor(acc[t], 4); red_xor(acc[t], 8);
            red_xor(acc[t], 16); red_xor(acc[t], 32);
        }
        if (r0 == 0) {
            const float4 bb = b1v[wave * 4 + c4l];
            #pragma unroll
            for (int t = 0; t < T; ++t) {
                float4 r;
                r.x = fmaxf(acc[t].x + bb.x, 0.f);
                r.y = fmaxf(acc[t].y + bb.y, 0.f);
                r.z = fmaxf(acc[t].z + bb.z, 0.f);
                r.w = fmaxf(acc[t].w + bb.w, 0.f);
                *(float4*)&vsm[t * VPAD + wave * 16 + c4l * 4] = r;
            }
        }
    }
    __syncthreads();

    // ---- phase 2: out += sc * (v @ W2 + b2), same 4-deep ring ----
    // wave covers cols [wave*32, wave*32+32); lane = (r8 = lane>>3, c8 = lane&7)
    {
        const int c8 = lane & 7, r8 = lane >> 3;
        float4 acc[T];
        #pragma unroll
        for (int t = 0; t < T; ++t) acc[t] = make_float4(0.f, 0.f, 0.f, 0.f);
        const float4* wp = w2v + (size_t)(r8 * 128 + wave * 8 + c8);
        const float*  vb = vsm + r8;
        float4 wr0 = wp[0], wr1 = wp[1024], wr2 = wp[2048], wr3 = wp[3072];
        #pragma unroll
        for (int sb = 0; sb < 32; sb += 4) {
            #pragma unroll
            for (int t = 0; t < T; ++t) fma4(acc[t], vb[t * VPAD + (sb + 0) * 8], wr0);
            if (sb < 28) wr0 = wp[(size_t)(sb + 4) * 1024];
            #pragma unroll
            for (int t = 0; t < T; ++t) fma4(acc[t], vb[t * VPAD + (sb + 1) * 8], wr1);
            if (sb < 28) wr1 = wp[(size_t)(sb + 5) * 1024];
            #pragma unroll
            for (int t = 0; t < T; ++t) fma4(acc[t], vb[t * VPAD + (sb + 2) * 8], wr2);
            if (sb < 28) wr2 = wp[(size_t)(sb + 6) * 1024];
            #pragma unroll
            for (int t = 0; t < T; ++t) fma4(acc[t], vb[t * VPAD + (sb + 3) * 8], wr3);
            if (sb < 28) wr3 = wp[(size_t)(sb + 7) * 1024];
        }
        #pragma unroll
        for (int t = 0; t < T; ++t) {      // reduce over r8 (lane bits 3..5)
            red_xor(acc[t], 8); red_xor(acc[t], 16); red_xor(acc[t], 32);
        }
        // butterfly leaves the full sum in every lane; spread the token loop
        // across r8 groups so all 64 lanes issue atomics (static t indexing).
        const float4 bb = b2v[wave * 8 + c8];
        #pragma unroll
        for (int t = 0; t < T; ++t) {
            if ((t & 7) == r8 && t < nTok) {
                const float sc = escv[t];
                float* o = out + (size_t)(slotIds[t] >> 1) * OUT_W
                               + (wave * 8 + c8) * 4;
                atomicAdd(o + 0, (acc[t].x + bb.x) * sc);
                atomicAdd(o + 1, (acc[t].y + bb.y) * sc);
                atomicAdd(o + 2, (acc[t].z + bb.z) * sc);
                atomicAdd(o + 3, (acc[t].w + bb.w) * sc);
            }
        }
    }
}

__global__ __launch_bounds__(1024, 4) void expert_kernel(
    const float* __restrict__ x,
    const float* __restrict__ w1s, const float* __restrict__ b1s,
    const float* __restrict__ w2s, const float* __restrict__ b2s,
    const int* __restrict__ counts, const int* __restrict__ lists,
    const float* __restrict__ esc, float* __restrict__ out)
{
    __shared__ __align__(16) float xs[T_CAP * XPAD];   // ~16.6 KB
    __shared__ __align__(16) float vsm[T_CAP * VPAD];  // ~8.4 KB
    __shared__ int   slotIds[T_CAP];
    __shared__ float escv[T_CAP];

    const int e  = blockIdx.x;
    const int g  = blockIdx.y;
    const int ne = min(counts[e], LIST_CAP);
    const int tid  = threadIdx.x;
    const int wave = tid >> 6, lane = tid & 63;

    const float4* w1v = (const float4*)(w1s + (size_t)e * IN_W * BLOCK_H);
    const float4* w2v = (const float4*)(w2s + (size_t)e * BLOCK_H * OUT_W);
    const float4* b1v = (const float4*)(b1s + (size_t)e * BLOCK_H);
    const float4* b2v = (const float4*)(b2s + (size_t)e * OUT_W);
    const float4* x4  = (const float4*)x;

    // pass p handles slot indices j = s0 + i*NGRP, i < T_CAP, s0 = g + p*32
    for (int s0 = g; s0 < ne; s0 += NGRP * T_CAP) {
        const int nTok  = min(T_CAP, (ne - s0 + NGRP - 1) / NGRP);
        const int Tpath = (nTok <= 4) ? 4 : 8;

        if (tid < T_CAP) {
            int s = 0; float sc = 0.f;
            if (tid < nTok) { s = lists[e * LIST_CAP + s0 + tid * NGRP]; sc = esc[s]; }
            slotIds[tid] = s;
            escv[tid]    = sc;
        }
        __syncthreads();

        // stage Tpath token rows (zero-pad missing)
        for (int idx = tid; idx < Tpath * 128; idx += 1024) {
            const int t = idx >> 7, q = idx & 127;
            float4 v = make_float4(0.f, 0.f, 0.f, 0.f);
            if (t < nTok) v = x4[(size_t)(slotIds[t] >> 1) * 128 + q];
            *(float4*)&xs[t * XPAD + q * 4] = v;
        }
        __syncthreads();

        if (nTok <= 4)
            run_pass<4>(nTok, wave, lane, w1v, w2v, b1v, b2v, xs, vsm, slotIds, escv, out);
        else
            run_pass<8>(nTok, wave, lane, w1v, w2v, b1v, b2v, xs, vsm, slotIds, escv, out);
        __syncthreads();   // xs/vsm reused next pass (ne > 32: ~47% of experts)
    }
}

extern "C" void kernel_launch(void* const* d_in, const int* in_sizes, int n_in,
                              void* d_out, int out_size, void* d_ws, size_t ws_size,
                              hipStream_t stream) {
    const float* x      = (const float*)d_in[0];
    const float* noise  = (const float*)d_in[1];
    const float* w1s    = (const float*)d_in[2];
    const float* b1s    = (const float*)d_in[3];
    const float* w2s    = (const float*)d_in[4];
    const float* b2s    = (const float*)d_in[5];
    const float* mixer  = (const float*)d_in[6];
    const float* noisec = (const float*)d_in[7];
    float* out = (float*)d_out;

    // workspace: ~41 KB total (keep FAR under ws_size)
    char* ws = (char*)d_ws;
    int*   counts = (int*)ws;                       ws += 256;
    float* esc    = (float*)ws;                     ws += NSLOTS * sizeof(float);
    int*   lists  = (int*)ws;   /* 64 * 128 ints = 32 KB */

    hipMemsetAsync(counts, 0, 256, stream);

    routing_kernel<<<TOKENS, 256, 0, stream>>>(x, noise, mixer, noisec,
                                               esc, counts, lists, out);
    expert_kernel<<<dim3(N_EXPERTS, NGRP), 1024, 0, stream>>>(
        x, w1s, b1s, w2s, b2s, counts, lists, esc, out);
}

// Round 10
// 179.561 us; speedup vs baseline: 1.3447x; 1.3447x over previous
//
#include <hip/hip_runtime.h>
#include <math.h>

#define TOKENS    1024
#define IN_W      512
#define BLOCK_H   256
#define OUT_W     512
#define N_EXPERTS 64
#define TOPK      2
#define NSLOTS    (TOKENS * TOPK)
#define LIST_CAP  128     // ne ~ Binom(2048,1/64): mean 32, sigma 5.6; 128 is +17 sigma
#define T_CAP     12      // max tokens per pass
#define NGRP      8       // groups/expert -> grid 512 = 2 blocks/CU co-resident
#define XPAD      520     // x row stride (floats); 2080 B, 16B-aligned
#define VPAD      264     // v row stride; 1056 B, 16B-aligned

__device__ __forceinline__ void red_xor(float4& v, int m) {
    v.x += __shfl_xor(v.x, m); v.y += __shfl_xor(v.y, m);
    v.z += __shfl_xor(v.z, m); v.w += __shfl_xor(v.w, m);
}

__device__ __forceinline__ void fma4(float4& a, float s, const float4& w) {
    a.x = fmaf(s, w.x, a.x); a.y = fmaf(s, w.y, a.y);
    a.z = fmaf(s, w.z, a.z); a.w = fmaf(s, w.w, a.w);
}

// ---------------------------------------------------------------------------
// Routing v2 (verified r7): 1 token/block x 1024 blocks; wave = i-quarter;
// float4 loads 4 rows x 64 experts; zeroes this token's out row.
// ---------------------------------------------------------------------------
__global__ __launch_bounds__(256) void routing_kernel(
    const float* __restrict__ x, const float* __restrict__ noise,
    const float* __restrict__ mixer, const float* __restrict__ noisec,
    float* __restrict__ esc, int* __restrict__ counts, int* __restrict__ lists,
    float* __restrict__ out)
{
    __shared__ float xs[512];
    __shared__ float pm[4 * 64];
    __shared__ float pn[4 * 64];
    __shared__ float hs[64];
    const int t    = blockIdx.x;
    const int tid  = threadIdx.x;
    const int wave = tid >> 6, lane = tid & 63;
    const int rs   = lane >> 4;
    const int c    = lane & 15;

    if (tid < 128) {
        ((float4*)xs)[tid] = ((const float4*)(x + (size_t)t * IN_W))[tid];
        ((float4*)(out + (size_t)t * OUT_W))[tid] = make_float4(0.f, 0.f, 0.f, 0.f);
    }
    __syncthreads();

    float4 am = make_float4(0.f, 0.f, 0.f, 0.f), an = am;
    const float4* m4 = (const float4*)mixer;
    const float4* n4 = (const float4*)noisec;
    const int rbase = wave * 128;
    #pragma unroll 4
    for (int j = 0; j < 32; ++j) {
        const int r = rbase + j * 4 + rs;
        const float xv = xs[r];
        const float4 wm = m4[r * 16 + c];
        const float4 wn = n4[r * 16 + c];
        fma4(am, xv, wm);
        fma4(an, xv, wn);
    }
    red_xor(am, 16); red_xor(am, 32);
    red_xor(an, 16); red_xor(an, 32);
    if (lane < 16) {
        *(float4*)&pm[wave * 64 + lane * 4] = am;
        *(float4*)&pn[wave * 64 + lane * 4] = an;
    }
    __syncthreads();

    if (tid < 64) {
        const float am2 = pm[tid] + pm[64 + tid] + pm[128 + tid] + pm[192 + tid];
        const float an2 = pn[tid] + pn[64 + tid] + pn[128 + tid] + pn[192 + tid];
        const float sp = fmaxf(an2, 0.f) + log1pf(expf(-fabsf(an2)));
        hs[tid] = am2 + noise[(size_t)t * 64 + tid] * sp;
    }
    __syncthreads();

    if (tid == 0) {
        float b0 = -INFINITY, b1 = -INFINITY;
        int i0 = 0, i1 = 0;
        for (int i = 0; i < N_EXPERTS; ++i) {
            const float v = hs[i];
            if (v > b0)      { b1 = b0; i1 = i0; b0 = v; i0 = i; }
            else if (v > b1) { b1 = v; i1 = i; }
        }
        const float z   = expf(b1 - b0);
        const float inv = 1.f / (1.f + z);
        esc[t * 2 + 0] = inv;
        esc[t * 2 + 1] = z * inv;
        const int p0 = atomicAdd(&counts[i0], 1);
        if (p0 < LIST_CAP) lists[i0 * LIST_CAP + p0] = t * 2 + 0;
        const int p1 = atomicAdd(&counts[i1], 1);
        if (p1 < LIST_CAP) lists[i1 * LIST_CAP + p1] = t * 2 + 1;
    }
}

// ---------------------------------------------------------------------------
// Fused expert FFN: r1's loop body VERBATIM (the only spill-free 53-us
// version; 5 manual-MLP attempts r2/r4/r5/r8/r9 all spilled at the 64-VGPR
// cap). Single change vs r7: NGRP 4->8 (grid 512 = 2 blocks/CU). r4 proved
// 2-block residency doubles occupancy (72%); its regression was solely the
// (1024,8) bound forcing VGPR 32. Here launch_bounds stays (1024,4): the
// compiler emits the proven 64-VGPR body, and 64 VGPR + 37.9 KB LDS fits
// TWO blocks/CU at runtime -> two independent barrier domains per SIMD
// (block B issues while block A drains). id%8 = e%8 keeps an expert's 8
// sibling groups on one XCD so L2 dedupes the doubled weight stream.
// ---------------------------------------------------------------------------
template<int T>
__device__ __forceinline__ void run_pass(
    int nTok, int wave, int lane,
    const float4* __restrict__ w1v, const float4* __restrict__ w2v,
    const float4* __restrict__ b1v, const float4* __restrict__ b2v,
    const float* __restrict__ xs, float* __restrict__ vsm,
    const int* __restrict__ slotIds, const float* __restrict__ escv,
    float* __restrict__ out)
{
    // ---- phase 1: v = relu(x @ W1 + b1) ----
    // wave covers cols [wave*16, wave*16+16); lane = (r0 = lane>>2, c4l = lane&3)
    // row = s*16 + r0; per instr: 16 row-chunks x 64 B = 1 KB unique weights.
    {
        const int c4l = lane & 3, r0 = lane >> 2;
        float4 acc[T];
        #pragma unroll
        for (int t = 0; t < T; ++t) acc[t] = make_float4(0.f, 0.f, 0.f, 0.f);
        const float4* wp = w1v + (size_t)(r0 * 64 + wave * 4 + c4l);
        const float*  xb = xs + r0;
        #pragma unroll 2
        for (int s = 0; s < 32; ++s) {
            const float4 w = wp[(size_t)s * 1024];   // rows s*16+r0, col f4 wave*4+c4l
            #pragma unroll
            for (int t = 0; t < T; ++t) {
                const float xv = xb[t * XPAD + s * 16];   // 16 banks, 4-lane broadcast
                acc[t].x = fmaf(xv, w.x, acc[t].x);
                acc[t].y = fmaf(xv, w.y, acc[t].y);
                acc[t].z = fmaf(xv, w.z, acc[t].z);
                acc[t].w = fmaf(xv, w.w, acc[t].w);
            }
        }
        #pragma unroll
        for (int t = 0; t < T; ++t) {      // reduce over r0 (lane bits 2..5)
            red_xor(acc[t], 4); red_xor(acc[t], 8);
            red_xor(acc[t], 16); red_xor(acc[t], 32);
        }
        if (r0 == 0) {
            const float4 bb = b1v[wave * 4 + c4l];
            #pragma unroll
            for (int t = 0; t < T; ++t) {
                float4 r;
                r.x = fmaxf(acc[t].x + bb.x, 0.f);
                r.y = fmaxf(acc[t].y + bb.y, 0.f);
                r.z = fmaxf(acc[t].z + bb.z, 0.f);
                r.w = fmaxf(acc[t].w + bb.w, 0.f);
                *(float4*)&vsm[t * VPAD + wave * 16 + c4l * 4] = r;
            }
        }
    }
    __syncthreads();

    // ---- phase 2: out += sc * (v @ W2 + b2), straight to global atomics ----
    // wave covers cols [wave*32, wave*32+32); lane = (r8 = lane>>3, c8 = lane&7)
    // row = s*8 + r8; per instr: 8 row-chunks x 128 B contiguous.
    {
        const int c8 = lane & 7, r8 = lane >> 3;
        float4 acc[T];
        #pragma unroll
        for (int t = 0; t < T; ++t) acc[t] = make_float4(0.f, 0.f, 0.f, 0.f);
        const float4* wp = w2v + (size_t)(r8 * 128 + wave * 8 + c8);
        const float*  vb = vsm + r8;
        #pragma unroll 2
        for (int s = 0; s < 32; ++s) {
            const float4 w = wp[(size_t)s * 1024];   // rows s*8+r8, col f4 wave*8+c8
            #pragma unroll
            for (int t = 0; t < T; ++t) {
                const float vv = vb[t * VPAD + s * 8];    // 8 banks, 8-lane broadcast
                acc[t].x = fmaf(vv, w.x, acc[t].x);
                acc[t].y = fmaf(vv, w.y, acc[t].y);
                acc[t].z = fmaf(vv, w.z, acc[t].z);
                acc[t].w = fmaf(vv, w.w, acc[t].w);
            }
        }
        #pragma unroll
        for (int t = 0; t < T; ++t) {      // reduce over r8 (lane bits 3..5)
            red_xor(acc[t], 8); red_xor(acc[t], 16); red_xor(acc[t], 32);
        }
        // butterfly leaves the full sum in every lane; spread the token loop
        // across r8 groups so all 64 lanes issue atomics (static t indexing).
        const float4 bb = b2v[wave * 8 + c8];
        #pragma unroll
        for (int t = 0; t < T; ++t) {
            if ((t & 7) == r8 && t < nTok) {
                const float sc = escv[t];
                float* o = out + (size_t)(slotIds[t] >> 1) * OUT_W
                               + (wave * 8 + c8) * 4;
                atomicAdd(o + 0, (acc[t].x + bb.x) * sc);
                atomicAdd(o + 1, (acc[t].y + bb.y) * sc);
                atomicAdd(o + 2, (acc[t].z + bb.z) * sc);
                atomicAdd(o + 3, (acc[t].w + bb.w) * sc);
            }
        }
    }
}

__global__ __launch_bounds__(1024, 4) void expert_kernel(
    const float* __restrict__ x,
    const float* __restrict__ w1s, const float* __restrict__ b1s,
    const float* __restrict__ w2s, const float* __restrict__ b2s,
    const int* __restrict__ counts, const int* __restrict__ lists,
    const float* __restrict__ esc, float* __restrict__ out)
{
    __shared__ __align__(16) float xs[T_CAP * XPAD];   // ~25.0 KB
    __shared__ __align__(16) float vsm[T_CAP * VPAD];  // ~12.7 KB
    __shared__ int   slotIds[T_CAP];
    __shared__ float escv[T_CAP];

    const int e  = blockIdx.x;
    const int g  = blockIdx.y;
    const int ne = min(counts[e], LIST_CAP);
    const int tid  = threadIdx.x;
    const int wave = tid >> 6, lane = tid & 63;

    const float4* w1v = (const float4*)(w1s + (size_t)e * IN_W * BLOCK_H);
    const float4* w2v = (const float4*)(w2s + (size_t)e * BLOCK_H * OUT_W);
    const float4* b1v = (const float4*)(b1s + (size_t)e * BLOCK_H);
    const float4* b2v = (const float4*)(b2s + (size_t)e * OUT_W);
    const float4* x4  = (const float4*)x;

    // pass p handles slot indices j = s0 + i*NGRP, i < T_CAP, s0 = g + p*96
    for (int s0 = g; s0 < ne; s0 += NGRP * T_CAP) {
        const int nTok  = min(T_CAP, (ne - s0 + NGRP - 1) / NGRP);
        const int Tpath = (nTok <= 4) ? 4 : (nTok <= 8) ? 8 : 12;

        if (tid < T_CAP) {
            int s = 0; float sc = 0.f;
            if (tid < nTok) { s = lists[e * LIST_CAP + s0 + tid * NGRP]; sc = esc[s]; }
            slotIds[tid] = s;
            escv[tid]    = sc;
        }
        __syncthreads();

        // stage Tpath token rows (zero-pad missing)
        for (int idx = tid; idx < Tpath * 128; idx += 1024) {
            const int t = idx >> 7, q = idx & 127;
            float4 v = make_float4(0.f, 0.f, 0.f, 0.f);
            if (t < nTok) v = x4[(size_t)(slotIds[t] >> 1) * 128 + q];
            *(float4*)&xs[t * XPAD + q * 4] = v;
        }
        __syncthreads();

        if (nTok <= 4)
            run_pass<4>(nTok, wave, lane, w1v, w2v, b1v, b2v, xs, vsm, slotIds, escv, out);
        else if (nTok <= 8)
            run_pass<8>(nTok, wave, lane, w1v, w2v, b1v, b2v, xs, vsm, slotIds, escv, out);
        else
            run_pass<12>(nTok, wave, lane, w1v, w2v, b1v, b2v, xs, vsm, slotIds, escv, out);
        __syncthreads();   // xs/vsm reused next pass (rare: ne > 96)
    }
}

extern "C" void kernel_launch(void* const* d_in, const int* in_sizes, int n_in,
                              void* d_out, int out_size, void* d_ws, size_t ws_size,
                              hipStream_t stream) {
    const float* x      = (const float*)d_in[0];
    const float* noise  = (const float*)d_in[1];
    const float* w1s    = (const float*)d_in[2];
    const float* b1s    = (const float*)d_in[3];
    const float* w2s    = (const float*)d_in[4];
    const float* b2s    = (const float*)d_in[5];
    const float* mixer  = (const float*)d_in[6];
    const float* noisec = (const float*)d_in[7];
    float* out = (float*)d_out;

    // workspace: ~41 KB total (keep FAR under ws_size)
    char* ws = (char*)d_ws;
    int*   counts = (int*)ws;                       ws += 256;
    float* esc    = (float*)ws;                     ws += NSLOTS * sizeof(float);
    int*   lists  = (int*)ws;   /* 64 * 128 ints = 32 KB */

    hipMemsetAsync(counts, 0, 256, stream);

    routing_kernel<<<TOKENS, 256, 0, stream>>>(x, noise, mixer, noisec,
                                               esc, counts, lists, out);
    expert_kernel<<<dim3(N_EXPERTS, NGRP), 1024, 0, stream>>>(
        x, w1s, b1s, w2s, b2s, counts, lists, esc, out);
}